// Round 10
// baseline (511.250 us; speedup 1.0000x reference)
//
#include <hip/hip_runtime.h>
#include <stdint.h>

#define B_ 8
#define N_ 4096
#define C_ 512
#define H_ 256
#define NC_ 1000

typedef float v4f __attribute__((ext_vector_type(4)));
typedef short v8s __attribute__((ext_vector_type(8)));
typedef unsigned short ushort_t;

__device__ __forceinline__ uint32_t f2bf1(float f) {
    uint32_t u = __float_as_uint(f);
    return (u + 0x7FFFu + ((u >> 16) & 1u)) >> 16;
}
__device__ __forceinline__ uint32_t pk2(float lo, float hi) {
#if __has_builtin(__builtin_amdgcn_cvt_pk_bf16_f32)
    auto r = __builtin_amdgcn_cvt_pk_bf16_f32(lo, hi);   // v_cvt_pk_bf16_f32
    return __builtin_bit_cast(uint32_t, r);
#else
    return f2bf1(lo) | (f2bf1(hi) << 16);
#endif
}

// ---- prep: proj_W -> bf16 B-fragment order + zero per-batch counters -------
// (gather is dead code: the permutation feeds a permutation-invariant mean)
__global__ void prep_kernel(const float* __restrict__ W, ushort_t* __restrict__ Wfrag,
                            uint32_t* __restrict__ counters) {
    int t = threadIdx.x;
    if (blockIdx.x == 0 && t < 8) counters[t] = 0;
    int i = blockIdx.x * 256 + t;                      // 0..32767 = d*64 + kb*4 + q
    int d = i >> 6, kb = (i >> 2) & 15, q = i & 3;
    const float4* src = (const float4*)(W + d * C_ + kb * 32 + q * 8);
    float4 v0 = src[0], v1 = src[1];
    uint4 pk;
    pk.x = pk2(v0.x, v0.y); pk.y = pk2(v0.z, v0.w);
    pk.z = pk2(v1.x, v1.y); pk.w = pk2(v1.z, v1.w);
    ((uint4*)Wfrag)[((d >> 4) * 16 + kb) * 64 + q * 16 + (d & 15)] = pk;
}

// one K-step of the MFMA loop (R7-proven form)
__device__ __forceinline__ void kstep(int kb, v4f (&acc)[4][4],
                                      const ushort_t* const (&fb)[4],
                                      const v8s* __restrict__ Abuf,
                                      int c, int q) {
    v8s af[4], bf[4];
#pragma unroll
    for (int nt = 0; nt < 4; nt++)
        bf[nt] = *((const v8s*)(fb[nt] + kb * 512));
#pragma unroll
    for (int mt = 0; mt < 4; mt++)
        af[mt] = Abuf[(mt * 16 + c) * 64 + ((kb * 4 + q) ^ (c & 7))];
#pragma unroll
    for (int mt = 0; mt < 4; mt++)
#pragma unroll
        for (int nt = 0; nt < 4; nt++)
            acc[mt][nt] = __builtin_amdgcn_mfma_f32_16x16x32_bf16(
                af[mt], bf[nt], acc[mt][nt], 0, 0, 0);
}

// ---- single fused kernel: gemm+LN+col-pool (512) + prev-pool (256) + head --
// R9 structure frozen. NEW: per-batch completion counter; the 96th (last)
// finisher block of each batch runs that batch's 3-layer MLP head inline
// (512-thread version, LDS aliased onto the then-dead Abuf). Removes the
// head_kernel dispatch entirely — testing the "fixed per-dispatch boundary
// cost" theory that R9's traffic-free-but-equal-time anomaly pointed to.
// No spinning: last-finisher pattern is safe under undefined dispatch order.
__global__ __launch_bounds__(512, 4)
void gemm_ln_pool(const float* __restrict__ feat, const float* __restrict__ prev,
                  const ushort_t* __restrict__ Wfrag,
                  const float* __restrict__ pb, const float* __restrict__ lg,
                  const float* __restrict__ lb,
                  float* __restrict__ partialG,      // [512][512]
                  float* __restrict__ partialP,      // [256][512]
                  uint32_t* __restrict__ counters,   // [8]
                  const float* __restrict__ W1, const float* __restrict__ b1,
                  const float* __restrict__ W2, const float* __restrict__ b2,
                  const float* __restrict__ W3, const float* __restrict__ b3,
                  float* __restrict__ out) {
    __shared__ v8s Abuf[4096];          // 64 rows x 64 chunks(16B), xor-swizzled
    __shared__ float RowS[64], RowQ[64];
    __shared__ int isLast;

    const int bid = blockIdx.x;
    const int t = threadIdx.x;
    int b;                                              // batch of this block

    if (bid % 3 == 2) {
        // ---- prev-pool role: column sums of a 128-row slab, no atomics ----
        const int p = bid / 3;                          // 0..255
        b = p >> 5;
        const int r0 = (p & 31) << 7;                   // 128-row slab
        const int col4 = t & 127, rg = t >> 7;          // 4 rowgroups x 32 rows
        const v4f* psrc =
            (const v4f*)(prev + (size_t)(b * N_ + r0 + rg * 32) * C_) + col4;
        v4f a0 = {0.f, 0.f, 0.f, 0.f}, a1 = a0, a2 = a0, a3 = a0;
#pragma unroll
        for (int batch = 0; batch < 4; batch++) {
            v4f v[8];
#pragma unroll
            for (int j = 0; j < 8; j++)
                v[j] = __builtin_nontemporal_load(psrc + (batch * 8 + j) * 128);
            a0 += v[0]; a1 += v[1]; a2 += v[2]; a3 += v[3];
            a0 += v[4]; a1 += v[5]; a2 += v[6]; a3 += v[7];
        }
        v4f s = (a0 + a1) + (a2 + a3);
        float* AbufF = (float*)Abuf;
        ((v4f*)AbufF)[rg * 128 + col4] = s;             // AbufF[rg][512 floats]
        __syncthreads();
        partialP[(size_t)p * 512 + t] =
            (AbufF[t] + AbufF[512 + t]) + (AbufF[1024 + t] + AbufF[1536 + t]);
    } else {
        const int gix = (bid / 3) * 2 + (bid % 3);      // 0..511
        b = gix >> 6;
        const int row0 = (gix & 63) << 6;
        const int wv = t >> 6, lane = t & 63, c = lane & 15, q = lane >> 4;

        if (t < 64) { RowS[t] = 0.f; RowQ[t] = 0.f; }

        // ---- phase 1a: stage K-half0 (chunks 0..31 -> cols 0..255) ----
        const int arow = t >> 3;                       // 0..63
        const int acol8 = t & 7;
        const v4f* asrc = (const v4f*)(feat + ((size_t)(b * N_ + row0 + arow) * C_));
#pragma unroll 2
        for (int s = 0; s < 4; s++) {
            const int chunk = s * 8 + acol8;
            v4f f0 = __builtin_nontemporal_load(asrc + chunk * 2);
            v4f f1 = __builtin_nontemporal_load(asrc + chunk * 2 + 1);
            uint4 pk;
            pk.x = pk2(f0.x, f0.y); pk.y = pk2(f0.z, f0.w);
            pk.z = pk2(f1.x, f1.y); pk.w = pk2(f1.z, f1.w);
            ((uint4*)Abuf)[arow * 64 + (chunk ^ (arow & 7))] = pk;
        }

        const ushort_t* fb[4];
#pragma unroll
        for (int nt = 0; nt < 4; nt++)
            fb[nt] = Wfrag + (wv * 4 + nt) * 8192 + lane * 8;

        v4f acc[4][4];
        const v4f vzero = {0.f, 0.f, 0.f, 0.f};
#pragma unroll
        for (int mt = 0; mt < 4; mt++)
#pragma unroll
            for (int nt = 0; nt < 4; nt++) acc[mt][nt] = vzero;

        __syncthreads();

        // ---- K-loop half0 (kb 0..5) ----
#pragma unroll 2
        for (int kb = 0; kb < 6; kb++) kstep(kb, acc, fb, Abuf, c, q);

        // ---- phase 1b: stage K-half1 mid-loop (chunks 32..63) ----
#pragma unroll 2
        for (int s = 4; s < 8; s++) {
            const int chunk = s * 8 + acol8;
            v4f f0 = __builtin_nontemporal_load(asrc + chunk * 2);
            v4f f1 = __builtin_nontemporal_load(asrc + chunk * 2 + 1);
            uint4 pk;
            pk.x = pk2(f0.x, f0.y); pk.y = pk2(f0.z, f0.w);
            pk.z = pk2(f1.x, f1.y); pk.w = pk2(f1.z, f1.w);
            ((uint4*)Abuf)[arow * 64 + (chunk ^ (arow & 7))] = pk;
        }

        kstep(6, acc, fb, Abuf, c, q);
        kstep(7, acc, fb, Abuf, c, q);
        __syncthreads();

        // ---- K-loop half1 (kb 8..15) ----
#pragma unroll 2
        for (int kb = 8; kb < 16; kb++) kstep(kb, acc, fb, Abuf, c, q);

        // ---- epilogue: bias, LN row stats, column pool ----
        float pb4[4], lg4[4], lb4[4];
#pragma unroll
        for (int nt = 0; nt < 4; nt++) {
            int n = wv * 64 + nt * 16 + c;
            pb4[nt] = pb[n]; lg4[nt] = lg[n]; lb4[nt] = lb[n];
        }
#pragma unroll
        for (int mt = 0; mt < 4; mt++) {
#pragma unroll
            for (int reg = 0; reg < 4; reg++) {
                float s1 = 0.f, s2 = 0.f;
#pragma unroll
                for (int nt = 0; nt < 4; nt++) {
                    float v = acc[mt][nt][reg] + pb4[nt];
                    acc[mt][nt][reg] = v;
                    s1 += v; s2 += v * v;
                }
#pragma unroll
                for (int d = 1; d < 16; d <<= 1) {
                    s1 += __shfl_xor(s1, d);
                    s2 += __shfl_xor(s2, d);
                }
                if (c == 0) {
                    int r = mt * 16 + q * 4 + reg;
                    atomicAdd(&RowS[r], s1);
                    atomicAdd(&RowQ[r], s2);
                }
            }
        }
        __syncthreads();
        if (t < 64) {
            float mu = RowS[t] * (1.f / C_);
            float var = RowQ[t] * (1.f / C_) - mu * mu;
            RowS[t] = mu;
            RowQ[t] = rsqrtf(var + 1e-5f);
        }
        __syncthreads();
        float col[4] = {0.f, 0.f, 0.f, 0.f};
#pragma unroll
        for (int mt = 0; mt < 4; mt++) {
#pragma unroll
            for (int reg = 0; reg < 4; reg++) {
                int r = mt * 16 + q * 4 + reg;
                float mu = RowS[r], rs = RowQ[r];
#pragma unroll
                for (int nt = 0; nt < 4; nt++)
                    col[nt] += (acc[mt][nt][reg] - mu) * rs * lg4[nt] + lb4[nt];
            }
        }
#pragma unroll
        for (int nt = 0; nt < 4; nt++) {
            col[nt] += __shfl_xor(col[nt], 16);
            col[nt] += __shfl_xor(col[nt], 32);
        }
        if (lane < 16) {
#pragma unroll
            for (int nt = 0; nt < 4; nt++)
                partialG[(size_t)gix * 512 + wv * 64 + nt * 16 + c] = col[nt];
        }
    }

    // ---- completion: 96 producers per batch; last one runs the head -------
    __threadfence();                     // release this thread's partial stores
    __syncthreads();
    if (t == 0) {
        uint32_t prev_cnt = atomicAdd(&counters[b], 1u);   // device-scope
        isLast = (prev_cnt == 95u);
    }
    __syncthreads();
    if (!isLast) return;
    __threadfence();                     // acquire other blocks' partials

    // ---- head tail (one block per batch, 512 threads) ----
    float* P  = (float*)Abuf;            // Abuf dead by now; alias 4KB of it
    float* H1 = P + 512;
    float* H2 = H1 + 256;
    {
        const float* pg = partialG + (size_t)b * 64 * 512 + t;
        const float* pp = partialP + (size_t)b * 32 * 512 + t;
        float a0 = 0.f, a1 = 0.f, a2 = 0.f, a3 = 0.f;
#pragma unroll 4
        for (int i = 0; i < 64; i += 4) {
            a0 += pg[(i + 0) * 512]; a1 += pg[(i + 1) * 512];
            a2 += pg[(i + 2) * 512]; a3 += pg[(i + 3) * 512];
        }
#pragma unroll 4
        for (int i = 0; i < 32; i += 4) {
            a0 += pp[(i + 0) * 512]; a1 += pp[(i + 1) * 512];
            a2 += pp[(i + 2) * 512]; a3 += pp[(i + 3) * 512];
        }
        P[t] = ((a0 + a1) + (a2 + a3)) * (1.f / 4096.f);
    }
    __syncthreads();

    // h1 (rows 0..255 on threads 0..255)
    {
        float s = 0.f;
        if (t < 256) {
            const float4* wr = (const float4*)(W1 + t * C_);
#pragma unroll 8
            for (int k = 0; k < 128; k++) {
                float4 w = wr[k];
                float4 p = ((const float4*)P)[k];
                s += w.x * p.x + w.y * p.y + w.z * p.z + w.w * p.w;
            }
        }
        __syncthreads();                 // P no longer needed after reads above
        if (t < 256) H1[t] = fmaxf(s + b1[t], 0.f);
    }
    __syncthreads();

    // h2
    {
        float s = 0.f;
        if (t < 256) {
            const float4* wr = (const float4*)(W2 + t * H_);
#pragma unroll 8
            for (int k = 0; k < 64; k++) {
                float4 w = wr[k];
                float4 p = ((const float4*)H1)[k];
                s += w.x * p.x + w.y * p.y + w.z * p.z + w.w * p.w;
            }
            H2[t] = fmaxf(s + b2[t], 0.f);
        }
    }
    __syncthreads();

    // layer 3: 1000 outputs, thread-per-output (two passes), W2/W3 L2-hot
    for (int o = t; o < NC_; o += 512) {
        const float4* wr = (const float4*)(W3 + o * H_);
        float s = 0.f;
#pragma unroll 8
        for (int k = 0; k < 64; k++) {
            float4 w = wr[k];
            float4 p = ((const float4*)H2)[k];
            s += w.x * p.x + w.y * p.y + w.z * p.z + w.w * p.w;
        }
        out[b * NC_ + o] = s + b3[o];
    }
}

extern "C" void kernel_launch(void* const* d_in, const int* in_sizes, int n_in,
                              void* d_out, int out_size, void* d_ws, size_t ws_size,
                              hipStream_t stream) {
    const float* feat  = (const float*)d_in[0];
    const float* prev  = (const float*)d_in[1];
    // d_in[2] = pos_org, d_in[3] = pos_shuffled — UNUSED: the gather is a row
    // permutation and the only consumer (token mean) is permutation-invariant.
    const float* projW = (const float*)d_in[4];
    const float* pb    = (const float*)d_in[5];
    const float* lg    = (const float*)d_in[6];
    const float* lb    = (const float*)d_in[7];
    const float* W1    = (const float*)d_in[8];
    const float* b1    = (const float*)d_in[9];
    const float* W2    = (const float*)d_in[10];
    const float* b2    = (const float*)d_in[11];
    const float* W3    = (const float*)d_in[12];
    const float* b3    = (const float*)d_in[13];
    float* out = (float*)d_out;

    char* ws = (char*)d_ws;
    ushort_t* Wfrag    = (ushort_t*)ws;                  // 524288 B (exact)
    float* partialG    = (float*)(ws + 524288);          // 512*512*4 = 1048576 B
    float* partialP    = (float*)(ws + 1572864);         // 256*512*4 =  524288 B
    uint32_t* counters = (uint32_t*)(ws + 2097152);      // 32 B

    prep_kernel<<<128, 256, 0, stream>>>(projW, Wfrag, counters);
    gemm_ln_pool<<<768, 512, 0, stream>>>(feat, prev, Wfrag, pb, lg, lb,
                                          partialG, partialP, counters,
                                          W1, b1, W2, b2, W3, b3, out);
}

// Round 11
// 220.316 us; speedup vs baseline: 2.3205x; 2.3205x over previous
//
#include <hip/hip_runtime.h>
#include <stdint.h>

#define B_ 8
#define N_ 4096
#define C_ 512
#define H_ 256
#define NC_ 1000

typedef float v4f __attribute__((ext_vector_type(4)));
typedef short v8s __attribute__((ext_vector_type(8)));
typedef unsigned short ushort_t;

__device__ __forceinline__ uint32_t f2bf1(float f) {
    uint32_t u = __float_as_uint(f);
    return (u + 0x7FFFu + ((u >> 16) & 1u)) >> 16;
}
__device__ __forceinline__ uint32_t pk2(float lo, float hi) {
#if __has_builtin(__builtin_amdgcn_cvt_pk_bf16_f32)
    auto r = __builtin_amdgcn_cvt_pk_bf16_f32(lo, hi);   // v_cvt_pk_bf16_f32
    return __builtin_bit_cast(uint32_t, r);
#else
    return f2bf1(lo) | (f2bf1(hi) << 16);
#endif
}

// ---- prep: proj_W -> bf16 B-fragment order only (gather is dead code: the
// permutation feeds a permutation-invariant token mean). --------------------
// Wfrag (uint4 units): slot[(ntile*16 + kb)*64 + q*16 + c] holds
// bf16(W[ntile*16+c][kb*32 + q*8 + j]), j=0..7.  (exact 524288 B)
__global__ void prep_kernel(const float* __restrict__ W, ushort_t* __restrict__ Wfrag) {
    int i = blockIdx.x * 256 + threadIdx.x;            // 0..32767 = d*64 + kb*4 + q
    int d = i >> 6, kb = (i >> 2) & 15, q = i & 3;
    const float4* src = (const float4*)(W + d * C_ + kb * 32 + q * 8);
    float4 v0 = src[0], v1 = src[1];
    uint4 pk;
    pk.x = pk2(v0.x, v0.y); pk.y = pk2(v0.z, v0.w);
    pk.z = pk2(v1.x, v1.y); pk.w = pk2(v1.z, v1.w);
    ((uint4*)Wfrag)[((d >> 4) * 16 + kb) * 64 + q * 16 + (d & 15)] = pk;
}

// ---- fused GEMM+bias+LN+col-pool (512 blocks) + prev-pool (256 blocks) ----
// PROVEN BEST (R7 = 217.8us total, gemm ~51us). 768 blocks, bid%3 roles,
// 2 blocks/CU co-residency for phase overlap, no global atomics (partials to
// workspace, R5 finding: device atomics on few cache lines serialize), no
// device fences (R10 finding: threadfence = L2 writeback on non-coherent
// XCDs, catastrophic). Six structural levers beyond this were tested and
// regressed or were neutral — this is the structure-invariant floor.
__global__ __launch_bounds__(512, 4)
void gemm_ln_pool(const float* __restrict__ feat, const float* __restrict__ prev,
                  const ushort_t* __restrict__ Wfrag,
                  const float* __restrict__ pb, const float* __restrict__ lg,
                  const float* __restrict__ lb,
                  float* __restrict__ partialG,      // [512][512]
                  float* __restrict__ partialP) {    // [256][512]
    __shared__ v8s Abuf[4096];          // 64 rows x 64 chunks(16B), xor-swizzled
    __shared__ float RowS[64], RowQ[64];

    const int bid = blockIdx.x;
    const int t = threadIdx.x;

    if (bid % 3 == 2) {
        // ---- prev-pool role: column sums of a 128-row slab, float4, no atomics
        const int p = bid / 3;                          // 0..255
        const int b = p >> 5;
        const int r0 = (p & 31) << 7;                   // 128-row slab
        const int col4 = t & 127, rg = t >> 7;          // 4 rowgroups x 32 rows
        const v4f* psrc =
            (const v4f*)(prev + (size_t)(b * N_ + r0 + rg * 32) * C_) + col4;
        v4f a0 = {0.f, 0.f, 0.f, 0.f}, a1 = a0, a2 = a0, a3 = a0;
#pragma unroll
        for (int batch = 0; batch < 4; batch++) {
            v4f v[8];
#pragma unroll
            for (int j = 0; j < 8; j++)
                v[j] = __builtin_nontemporal_load(psrc + (batch * 8 + j) * 128);
            a0 += v[0]; a1 += v[1]; a2 += v[2]; a3 += v[3];
            a0 += v[4]; a1 += v[5]; a2 += v[6]; a3 += v[7];
        }
        v4f s = (a0 + a1) + (a2 + a3);
        // combine 4 rowgroups via plain LDS stores (no atomics)
        float* AbufF = (float*)Abuf;
        ((v4f*)AbufF)[rg * 128 + col4] = s;             // AbufF[rg][512 floats]
        __syncthreads();
        partialP[(size_t)p * 512 + t] =
            (AbufF[t] + AbufF[512 + t]) + (AbufF[1024 + t] + AbufF[1536 + t]);
        return;
    }

    const int gix = (bid / 3) * 2 + (bid % 3);          // 0..511
    const int b = gix >> 6;
    const int row0 = (gix & 63) << 6;
    const int wv = t >> 6, lane = t & 63, c = lane & 15, q = lane >> 4;

    if (t < 64) { RowS[t] = 0.f; RowQ[t] = 0.f; }

    // ---- phase 1: stage A tile (sequential rows, fp32->bf16), nt loads ----
    const int arow = t >> 3;                           // 0..63
    const int acol8 = t & 7;
    const v4f* asrc = (const v4f*)(feat + ((size_t)(b * N_ + row0 + arow) * C_));
#pragma unroll 4
    for (int s = 0; s < 8; s++) {
        const int chunk = s * 8 + acol8;               // logical 16B-chunk 0..63
        v4f f0 = __builtin_nontemporal_load(asrc + chunk * 2);
        v4f f1 = __builtin_nontemporal_load(asrc + chunk * 2 + 1);
        uint4 pk;
        pk.x = pk2(f0.x, f0.y); pk.y = pk2(f0.z, f0.w);
        pk.z = pk2(f1.x, f1.y); pk.w = pk2(f1.z, f1.w);
        ((uint4*)Abuf)[arow * 64 + (chunk ^ (arow & 7))] = pk;
    }

    // B fragment bases: wave wv owns cols [64*wv, 64*wv+64), ntile = wv*4+nt
    const ushort_t* fb[4];
#pragma unroll
    for (int nt = 0; nt < 4; nt++)
        fb[nt] = Wfrag + (wv * 4 + nt) * 8192 + lane * 8;

    v4f acc[4][4];
    const v4f vzero = {0.f, 0.f, 0.f, 0.f};
#pragma unroll
    for (int mt = 0; mt < 4; mt++)
#pragma unroll
        for (int nt = 0; nt < 4; nt++) acc[mt][nt] = vzero;

    __syncthreads();

    // ---- phase 2: barrier-free K loop, only L2/L3-hit B loads in vm queue
#pragma unroll 2
    for (int kb = 0; kb < 16; kb++) {
        v8s af[4], bf[4];
#pragma unroll
        for (int nt = 0; nt < 4; nt++)
            bf[nt] = *((const v8s*)(fb[nt] + kb * 512));
#pragma unroll
        for (int mt = 0; mt < 4; mt++)
            af[mt] = Abuf[(mt * 16 + c) * 64 + ((kb * 4 + q) ^ (c & 7))];
#pragma unroll
        for (int mt = 0; mt < 4; mt++)
#pragma unroll
            for (int nt = 0; nt < 4; nt++)
                acc[mt][nt] = __builtin_amdgcn_mfma_f32_16x16x32_bf16(
                    af[mt], bf[nt], acc[mt][nt], 0, 0, 0);
    }

    // ---- epilogue: bias, LN row stats (LDS atomics on-CU), column pool ----
    float pb4[4], lg4[4], lb4[4];
#pragma unroll
    for (int nt = 0; nt < 4; nt++) {
        int n = wv * 64 + nt * 16 + c;
        pb4[nt] = pb[n]; lg4[nt] = lg[n]; lb4[nt] = lb[n];
    }
#pragma unroll
    for (int mt = 0; mt < 4; mt++) {
#pragma unroll
        for (int reg = 0; reg < 4; reg++) {
            float s1 = 0.f, s2 = 0.f;
#pragma unroll
            for (int nt = 0; nt < 4; nt++) {
                float v = acc[mt][nt][reg] + pb4[nt];
                acc[mt][nt][reg] = v;
                s1 += v; s2 += v * v;
            }
#pragma unroll
            for (int d = 1; d < 16; d <<= 1) {
                s1 += __shfl_xor(s1, d);
                s2 += __shfl_xor(s2, d);
            }
            if (c == 0) {
                int r = mt * 16 + q * 4 + reg;
                atomicAdd(&RowS[r], s1);
                atomicAdd(&RowQ[r], s2);
            }
        }
    }
    __syncthreads();
    if (t < 64) {
        float mu = RowS[t] * (1.f / C_);
        float var = RowQ[t] * (1.f / C_) - mu * mu;
        RowS[t] = mu;
        RowQ[t] = rsqrtf(var + 1e-5f);
    }
    __syncthreads();
    float col[4] = {0.f, 0.f, 0.f, 0.f};
#pragma unroll
    for (int mt = 0; mt < 4; mt++) {
#pragma unroll
        for (int reg = 0; reg < 4; reg++) {
            int r = mt * 16 + q * 4 + reg;
            float mu = RowS[r], rs = RowQ[r];
#pragma unroll
            for (int nt = 0; nt < 4; nt++)
                col[nt] += (acc[mt][nt][reg] - mu) * rs * lg4[nt] + lb4[nt];
        }
    }
#pragma unroll
    for (int nt = 0; nt < 4; nt++) {
        col[nt] += __shfl_xor(col[nt], 16);
        col[nt] += __shfl_xor(col[nt], 32);
    }
    // direct per-wave partial store (16 consecutive floats per nt = 64B)
    if (lane < 16) {
#pragma unroll
        for (int nt = 0; nt < 4; nt++)
            partialG[(size_t)gix * 512 + wv * 64 + nt * 16 + c] = col[nt];
    }
}

// ---- head: fused partial-reduce + 3-layer MLP. Each block redundantly sums
// the 96 partial rows (L2-hot, 196KB/block), then h1,h2 redundant + a
// 40-output slice of layer 3 (wave-per-output). ------------------------------
__global__ __launch_bounds__(256)
void head_kernel(const float* __restrict__ partialG,
                 const float* __restrict__ partialP,
                 const float* __restrict__ W1, const float* __restrict__ b1,
                 const float* __restrict__ W2, const float* __restrict__ b2,
                 const float* __restrict__ W3, const float* __restrict__ b3,
                 float* __restrict__ out) {
    __shared__ __align__(16) float P[512];
    __shared__ __align__(16) float H1[256];
    __shared__ __align__(16) float H2[256];
    const int t = threadIdx.x, wv = t >> 6, lane = t & 63;
    const int b = blockIdx.x / 25;
    const int slice = blockIdx.x % 25;                 // 25 slices x 40 outputs

    // fused reduction: cols t and t+256 over 64 gemm + 32 prev partial rows
    {
        const float* pg = partialG + (size_t)b * 64 * 512;
        const float* pp = partialP + (size_t)b * 32 * 512;
        float a0 = 0.f, a1 = 0.f, a2 = 0.f, a3 = 0.f;
#pragma unroll 4
        for (int i = 0; i < 64; i += 2) {
            a0 += pg[i * 512 + t];
            a1 += pg[(i + 1) * 512 + t];
            a2 += pg[i * 512 + t + 256];
            a3 += pg[(i + 1) * 512 + t + 256];
        }
#pragma unroll 4
        for (int i = 0; i < 32; i += 2) {
            a0 += pp[i * 512 + t];
            a1 += pp[(i + 1) * 512 + t];
            a2 += pp[i * 512 + t + 256];
            a3 += pp[(i + 1) * 512 + t + 256];
        }
        P[t] = (a0 + a1) * (1.f / 4096.f);
        P[t + 256] = (a2 + a3) * (1.f / 4096.f);
    }
    __syncthreads();

    // h1[t] = relu(W1[t,:] . P + b1[t])   (128 independent float4 loads)
    {
        const float4* wr = (const float4*)(W1 + t * C_);
        float s = 0.f;
#pragma unroll 8
        for (int k = 0; k < 128; k++) {
            float4 w = wr[k];
            float4 p = ((const float4*)P)[k];
            s += w.x * p.x + w.y * p.y + w.z * p.z + w.w * p.w;
        }
        H1[t] = fmaxf(s + b1[t], 0.f);
    }
    __syncthreads();

    // h2[t] = relu(W2[t,:] . H1 + b2[t])
    {
        const float4* wr = (const float4*)(W2 + t * H_);
        float s = 0.f;
#pragma unroll 8
        for (int k = 0; k < 64; k++) {
            float4 w = wr[k];
            float4 p = ((const float4*)H1)[k];
            s += w.x * p.x + w.y * p.y + w.z * p.z + w.w * p.w;
        }
        H2[t] = fmaxf(s + b2[t], 0.f);
    }
    __syncthreads();

    // layer 3: this block's 40 outputs, wave-per-output (coalesced W3 row)
#pragma unroll
    for (int jj = 0; jj < 10; jj++) {
        const int o = slice * 40 + jj * 4 + wv;
        float4 w = ((const float4*)(W3 + o * H_))[lane];
        float4 p = ((const float4*)H2)[lane];
        float s = w.x * p.x + w.y * p.y + w.z * p.z + w.w * p.w;
#pragma unroll
        for (int d = 1; d < 64; d <<= 1) s += __shfl_xor(s, d);
        if (lane == 0) out[b * NC_ + o] = s + b3[o];
    }
}

extern "C" void kernel_launch(void* const* d_in, const int* in_sizes, int n_in,
                              void* d_out, int out_size, void* d_ws, size_t ws_size,
                              hipStream_t stream) {
    const float* feat  = (const float*)d_in[0];
    const float* prev  = (const float*)d_in[1];
    // d_in[2] = pos_org, d_in[3] = pos_shuffled — UNUSED: the gather is a row
    // permutation and the only consumer (token mean) is permutation-invariant.
    const float* projW = (const float*)d_in[4];
    const float* pb    = (const float*)d_in[5];
    const float* lg    = (const float*)d_in[6];
    const float* lb    = (const float*)d_in[7];
    const float* W1    = (const float*)d_in[8];
    const float* b1    = (const float*)d_in[9];
    const float* W2    = (const float*)d_in[10];
    const float* b2    = (const float*)d_in[11];
    const float* W3    = (const float*)d_in[12];
    const float* b3    = (const float*)d_in[13];
    float* out = (float*)d_out;

    char* ws = (char*)d_ws;
    ushort_t* Wfrag  = (ushort_t*)ws;                    // 524288 B (exact)
    float* partialG  = (float*)(ws + 524288);            // 512*512*4 = 1048576 B
    float* partialP  = (float*)(ws + 1572864);           // 256*512*4 =  524288 B

    prep_kernel<<<128, 256, 0, stream>>>(projW, Wfrag);
    gemm_ln_pool<<<768, 512, 0, stream>>>(feat, prev, Wfrag,
                                          pb, lg, lb, partialG, partialP);
    head_kernel<<<200, 256, 0, stream>>>(partialG, partialP,
                                         W1, b1, W2, b2, W3, b3, out);
}

// Round 12
// 214.692 us; speedup vs baseline: 2.3813x; 1.0262x over previous
//
#include <hip/hip_runtime.h>
#include <stdint.h>

#define B_ 8
#define N_ 4096
#define C_ 512
#define H_ 256
#define NC_ 1000

typedef float v4f __attribute__((ext_vector_type(4)));
typedef short v8s __attribute__((ext_vector_type(8)));
typedef unsigned short ushort_t;

__device__ __forceinline__ uint32_t f2bf1(float f) {
    uint32_t u = __float_as_uint(f);
    return (u + 0x7FFFu + ((u >> 16) & 1u)) >> 16;
}
__device__ __forceinline__ uint32_t pk2(float lo, float hi) {
#if __has_builtin(__builtin_amdgcn_cvt_pk_bf16_f32)
    auto r = __builtin_amdgcn_cvt_pk_bf16_f32(lo, hi);   // v_cvt_pk_bf16_f32
    return __builtin_bit_cast(uint32_t, r);
#else
    return f2bf1(lo) | (f2bf1(hi) << 16);
#endif
}

// ---- prep: proj_W -> bf16 B-fragment order only (gather is dead code: the
// permutation feeds a permutation-invariant token mean). --------------------
// Wfrag (uint4 units): slot[(ntile*16 + kb)*64 + q*16 + c] holds
// bf16(W[ntile*16+c][kb*32 + q*8 + j]), j=0..7.  (exact 524288 B)
__global__ void prep_kernel(const float* __restrict__ W, ushort_t* __restrict__ Wfrag) {
    int i = blockIdx.x * 256 + threadIdx.x;            // 0..32767 = d*64 + kb*4 + q
    int d = i >> 6, kb = (i >> 2) & 15, q = i & 3;
    const float4* src = (const float4*)(W + d * C_ + kb * 32 + q * 8);
    float4 v0 = src[0], v1 = src[1];
    uint4 pk;
    pk.x = pk2(v0.x, v0.y); pk.y = pk2(v0.z, v0.w);
    pk.z = pk2(v1.x, v1.y); pk.w = pk2(v1.z, v1.w);
    ((uint4*)Wfrag)[((d >> 4) * 16 + kb) * 64 + q * 16 + (d & 15)] = pk;
}

// ---- fused GEMM+bias+LN+col-pool + prev-pool, 512 blocks = EXACTLY 2/CU ----
// R11 ledger: pure-gemm ~34us (R5) vs fused-768 ~51us = the 1.5-round ragged
// tail (768 blocks on 512 residency slots). Fix: each block also pools its
// OWN 64-row prev slab, folded into the epilogue (NOT phase 1 — R1 showed
// pre-K-loop prev loads + LDS-atomic drain poison the vm queue). Prev loads
// go in two 8-deep v4f batches interleaved with epilogue phases; rowgroup
// combine through the then-dead Abuf; result added into the same partialG
// row, so partialP and the head's second reduction loop disappear.
// Register budget: acc 64 + pv[8] 32 + temps ~ 115 < 128 cap (launch_bounds
// 512,4). Spill sentinel: WRITE_SIZE (~1.3MB expected).
__global__ __launch_bounds__(512, 4)
void gemm_ln_pool(const float* __restrict__ feat, const float* __restrict__ prev,
                  const ushort_t* __restrict__ Wfrag,
                  const float* __restrict__ pb, const float* __restrict__ lg,
                  const float* __restrict__ lb,
                  float* __restrict__ partialG) {    // [512][512]
    __shared__ v8s Abuf[4096];          // 64KB A-tile; reused as prev scratch
    __shared__ float RowS[64], RowQ[64], ColS[512];

    const int gix = blockIdx.x;                         // 0..511
    const int t = threadIdx.x;
    const int b = gix >> 6;
    const int row0 = (gix & 63) << 6;
    const int wv = t >> 6, lane = t & 63, c = lane & 15, q = lane >> 4;

    if (t < 64) { RowS[t] = 0.f; RowQ[t] = 0.f; }

    // ---- phase 1: stage A tile (sequential rows, fp32->bf16), nt loads ----
    const int arow = t >> 3;                           // 0..63
    const int acol8 = t & 7;
    const v4f* asrc = (const v4f*)(feat + ((size_t)(b * N_ + row0 + arow) * C_));
#pragma unroll 4
    for (int s = 0; s < 8; s++) {
        const int chunk = s * 8 + acol8;               // logical 16B-chunk 0..63
        v4f f0 = __builtin_nontemporal_load(asrc + chunk * 2);
        v4f f1 = __builtin_nontemporal_load(asrc + chunk * 2 + 1);
        uint4 pk;
        pk.x = pk2(f0.x, f0.y); pk.y = pk2(f0.z, f0.w);
        pk.z = pk2(f1.x, f1.y); pk.w = pk2(f1.z, f1.w);
        ((uint4*)Abuf)[arow * 64 + (chunk ^ (arow & 7))] = pk;
    }

    // B fragment bases: wave wv owns cols [64*wv, 64*wv+64), ntile = wv*4+nt
    const ushort_t* fb[4];
#pragma unroll
    for (int nt = 0; nt < 4; nt++)
        fb[nt] = Wfrag + (wv * 4 + nt) * 8192 + lane * 8;

    v4f acc[4][4];
    const v4f vzero = {0.f, 0.f, 0.f, 0.f};
#pragma unroll
    for (int mt = 0; mt < 4; mt++)
#pragma unroll
        for (int nt = 0; nt < 4; nt++) acc[mt][nt] = vzero;

    __syncthreads();

    // ---- phase 2: barrier-free K loop, only L2/L3-hit B loads in vm queue
#pragma unroll 2
    for (int kb = 0; kb < 16; kb++) {
        v8s af[4], bf[4];
#pragma unroll
        for (int nt = 0; nt < 4; nt++)
            bf[nt] = *((const v8s*)(fb[nt] + kb * 512));
#pragma unroll
        for (int mt = 0; mt < 4; mt++)
            af[mt] = Abuf[(mt * 16 + c) * 64 + ((kb * 4 + q) ^ (c & 7))];
#pragma unroll
        for (int mt = 0; mt < 4; mt++)
#pragma unroll
            for (int nt = 0; nt < 4; nt++)
                acc[mt][nt] = __builtin_amdgcn_mfma_f32_16x16x32_bf16(
                    af[mt], bf[nt], acc[mt][nt], 0, 0, 0);
    }

    // ---- prev batch 0: issue 8 v4f loads; latency hides under the bias/stats
    // VALU pass below (thread t: float4-col t&127, rowgroup t>>7 of 16 rows)
    const int col4 = t & 127, rg = t >> 7;
    const v4f* psrc =
        (const v4f*)(prev + (size_t)(b * N_ + row0 + rg * 16) * C_) + col4;
    v4f pv[8];
#pragma unroll
    for (int r = 0; r < 8; r++)
        pv[r] = __builtin_nontemporal_load(psrc + r * 128);

    // ---- epilogue pass 1: bias, LN row stats (LDS atomics on-CU) ----
    float pb4[4], lg4[4], lb4[4];
#pragma unroll
    for (int nt = 0; nt < 4; nt++) {
        int n = wv * 64 + nt * 16 + c;
        pb4[nt] = pb[n]; lg4[nt] = lg[n]; lb4[nt] = lb[n];
    }
#pragma unroll
    for (int mt = 0; mt < 4; mt++) {
#pragma unroll
        for (int reg = 0; reg < 4; reg++) {
            float s1 = 0.f, s2 = 0.f;
#pragma unroll
            for (int nt = 0; nt < 4; nt++) {
                float v = acc[mt][nt][reg] + pb4[nt];
                acc[mt][nt][reg] = v;
                s1 += v; s2 += v * v;
            }
#pragma unroll
            for (int d = 1; d < 16; d <<= 1) {
                s1 += __shfl_xor(s1, d);
                s2 += __shfl_xor(s2, d);
            }
            if (c == 0) {
                int r = mt * 16 + q * 4 + reg;
                atomicAdd(&RowS[r], s1);
                atomicAdd(&RowQ[r], s2);
            }
        }
    }
    __syncthreads();
    if (t < 64) {
        float mu = RowS[t] * (1.f / C_);
        float var = RowQ[t] * (1.f / C_) - mu * mu;
        RowS[t] = mu;
        RowQ[t] = rsqrtf(var + 1e-5f);
    }
    // consume prev batch 0; issue batch 1 (hides under stats barrier + col pass)
    v4f ps0 = (pv[0] + pv[1]) + (pv[2] + pv[3]);
    v4f ps1 = (pv[4] + pv[5]) + (pv[6] + pv[7]);
#pragma unroll
    for (int r = 0; r < 8; r++)
        pv[r] = __builtin_nontemporal_load(psrc + (8 + r) * 128);
    __syncthreads();

    // consume batch 1; stash rowgroup sum in Abuf (dead since K-loop + barrier)
    {
        v4f ps = (ps0 + ps1) +
                 ((pv[0] + pv[1]) + (pv[2] + pv[3])) +
                 ((pv[4] + pv[5]) + (pv[6] + pv[7]));
        float* AbufF = (float*)Abuf;
        ((v4f*)AbufF)[rg * 128 + col4] = ps;            // AbufF[rg][512 floats]
    }

    // ---- epilogue pass 2: normalize + column pool ----
    float col[4] = {0.f, 0.f, 0.f, 0.f};
#pragma unroll
    for (int mt = 0; mt < 4; mt++) {
#pragma unroll
        for (int reg = 0; reg < 4; reg++) {
            int r = mt * 16 + q * 4 + reg;
            float mu = RowS[r], rs = RowQ[r];
#pragma unroll
            for (int nt = 0; nt < 4; nt++)
                col[nt] += (acc[mt][nt][reg] - mu) * rs * lg4[nt] + lb4[nt];
        }
    }
#pragma unroll
    for (int nt = 0; nt < 4; nt++) {
        col[nt] += __shfl_xor(col[nt], 16);
        col[nt] += __shfl_xor(col[nt], 32);
    }
    if (lane < 16) {
#pragma unroll
        for (int nt = 0; nt < 4; nt++) ColS[wv * 64 + nt * 16 + c] = col[nt];
    }
    __syncthreads();

    // ---- combined partial row: LN column sums + prev column sums ----
    {
        const float* AbufF = (const float*)Abuf;
        float prevc = (AbufF[t] + AbufF[512 + t]) +
                      (AbufF[1024 + t] + AbufF[1536 + t]);
        partialG[(size_t)gix * 512 + t] = ColS[t] + prevc;
    }
}

// ---- head: fused partial-reduce + 3-layer MLP. Each block redundantly sums
// the 64 partial rows (L2-hot, 128KB/block), then h1,h2 redundant + a
// 40-output slice of layer 3 (wave-per-output). ------------------------------
__global__ __launch_bounds__(256)
void head_kernel(const float* __restrict__ partialG,
                 const float* __restrict__ W1, const float* __restrict__ b1,
                 const float* __restrict__ W2, const float* __restrict__ b2,
                 const float* __restrict__ W3, const float* __restrict__ b3,
                 float* __restrict__ out) {
    __shared__ __align__(16) float P[512];
    __shared__ __align__(16) float H1[256];
    __shared__ __align__(16) float H2[256];
    const int t = threadIdx.x, wv = t >> 6, lane = t & 63;
    const int b = blockIdx.x / 25;
    const int slice = blockIdx.x % 25;                 // 25 slices x 40 outputs

    // fused reduction: cols t and t+256 over 64 combined partial rows
    {
        const float* pg = partialG + (size_t)b * 64 * 512;
        float a0 = 0.f, a1 = 0.f, a2 = 0.f, a3 = 0.f;
#pragma unroll 4
        for (int i = 0; i < 64; i += 2) {
            a0 += pg[i * 512 + t];
            a1 += pg[(i + 1) * 512 + t];
            a2 += pg[i * 512 + t + 256];
            a3 += pg[(i + 1) * 512 + t + 256];
        }
        P[t] = (a0 + a1) * (1.f / 4096.f);
        P[t + 256] = (a2 + a3) * (1.f / 4096.f);
    }
    __syncthreads();

    // h1[t] = relu(W1[t,:] . P + b1[t])   (128 independent float4 loads)
    {
        const float4* wr = (const float4*)(W1 + t * C_);
        float s = 0.f;
#pragma unroll 8
        for (int k = 0; k < 128; k++) {
            float4 w = wr[k];
            float4 p = ((const float4*)P)[k];
            s += w.x * p.x + w.y * p.y + w.z * p.z + w.w * p.w;
        }
        H1[t] = fmaxf(s + b1[t], 0.f);
    }
    __syncthreads();

    // h2[t] = relu(W2[t,:] . H1 + b2[t])
    {
        const float4* wr = (const float4*)(W2 + t * H_);
        float s = 0.f;
#pragma unroll 8
        for (int k = 0; k < 64; k++) {
            float4 w = wr[k];
            float4 p = ((const float4*)H1)[k];
            s += w.x * p.x + w.y * p.y + w.z * p.z + w.w * p.w;
        }
        H2[t] = fmaxf(s + b2[t], 0.f);
    }
    __syncthreads();

    // layer 3: this block's 40 outputs, wave-per-output (coalesced W3 row)
#pragma unroll
    for (int jj = 0; jj < 10; jj++) {
        const int o = slice * 40 + jj * 4 + wv;
        float4 w = ((const float4*)(W3 + o * H_))[lane];
        float4 p = ((const float4*)H2)[lane];
        float s = w.x * p.x + w.y * p.y + w.z * p.z + w.w * p.w;
#pragma unroll
        for (int d = 1; d < 64; d <<= 1) s += __shfl_xor(s, d);
        if (lane == 0) out[b * NC_ + o] = s + b3[o];
    }
}

extern "C" void kernel_launch(void* const* d_in, const int* in_sizes, int n_in,
                              void* d_out, int out_size, void* d_ws, size_t ws_size,
                              hipStream_t stream) {
    const float* feat  = (const float*)d_in[0];
    const float* prev  = (const float*)d_in[1];
    // d_in[2] = pos_org, d_in[3] = pos_shuffled — UNUSED: the gather is a row
    // permutation and the only consumer (token mean) is permutation-invariant.
    const float* projW = (const float*)d_in[4];
    const float* pb    = (const float*)d_in[5];
    const float* lg    = (const float*)d_in[6];
    const float* lb    = (const float*)d_in[7];
    const float* W1    = (const float*)d_in[8];
    const float* b1    = (const float*)d_in[9];
    const float* W2    = (const float*)d_in[10];
    const float* b2    = (const float*)d_in[11];
    const float* W3    = (const float*)d_in[12];
    const float* b3    = (const float*)d_in[13];
    float* out = (float*)d_out;

    char* ws = (char*)d_ws;
    ushort_t* Wfrag  = (ushort_t*)ws;                    // 524288 B (exact)
    float* partialG  = (float*)(ws + 524288);            // 512*512*4 = 1048576 B

    prep_kernel<<<128, 256, 0, stream>>>(projW, Wfrag);
    gemm_ln_pool<<<512, 512, 0, stream>>>(feat, prev, Wfrag,
                                          pb, lg, lb, partialG);
    head_kernel<<<200, 256, 0, stream>>>(partialG,
                                         W1, b1, W2, b2, W3, b3, out);
}